// Round 2
// baseline (196.780 us; speedup 1.0000x reference)
//
#include <hip/hip_runtime.h>
#include <stdint.h>

// Problem constants (fixed by the reference).
#define BB 32
#define HH 512
#define WW 512
#define HWSZ (HH * WW)        // 262144 elements per batch
#define PP 8192               // samples per batch
#define WPB (HWSZ / 64)       // 4096 bitmap words per batch
#define EPSV 1e-5f

// ---------------------------------------------------------------------------
// K1: build per-wave 64-bit mask bitmap. gid = element index over B*HW.
// Each wave's __ballot produces one word; bit l <-> element (word_base + l).
// Also zeroes the accumulators (ws is re-poisoned to 0xAA before every call).
// ---------------------------------------------------------------------------
__global__ __launch_bounds__(256) void k_bitmap(const int* __restrict__ mask,
                                                uint64_t* __restrict__ words,
                                                float* __restrict__ accf,
                                                uint32_t* __restrict__ accu) {
    int gid = blockIdx.x * 256 + threadIdx.x;
    int m = mask[gid];
    unsigned long long ball = __ballot(m != 0);
    if ((threadIdx.x & 63) == 0) {
        words[gid >> 6] = (uint64_t)ball;
    }
    if (blockIdx.x == 0 && threadIdx.x == 0) {
        accf[0] = 0.0f; accf[1] = 0.0f;
        accu[0] = 0u; accu[1] = 0u; accu[2] = 0u;
    }
}

// ---------------------------------------------------------------------------
// K2: per-batch exclusive prefix of word popcounts + total valid count.
// One block (256 threads) per batch. Parallel shuffle scan (no serial loop).
// ---------------------------------------------------------------------------
__global__ __launch_bounds__(256) void k_scan(const uint64_t* __restrict__ words,
                                              uint32_t* __restrict__ wprefix,
                                              uint32_t* __restrict__ valid_num) {
    __shared__ uint32_t wsum[4];
    int b = blockIdx.x;
    int t = threadIdx.x;
    int lane = t & 63;
    int wid = t >> 6;
    const uint64_t* wb = words + (size_t)b * WPB;
    uint32_t pc[16];
    uint32_t s = 0;
    int base = t * 16;
#pragma unroll
    for (int i = 0; i < 16; ++i) {
        pc[i] = (uint32_t)__popcll(wb[base + i]);
        s += pc[i];
    }
    uint32_t own = s;
    // inclusive scan within wave (64 lanes)
#pragma unroll
    for (int off = 1; off < 64; off <<= 1) {
        uint32_t n = __shfl_up(s, off);
        if (lane >= off) s += n;
    }
    if (lane == 63) wsum[wid] = s;
    __syncthreads();
    uint32_t wbase = 0;
#pragma unroll
    for (int i = 0; i < 4; ++i) {
        if (i < wid) wbase += wsum[i];
    }
    uint32_t excl = wbase + s - own;   // exclusive prefix of this thread's 16 words
    if (t == 255) valid_num[b] = wbase + s;
    uint32_t off2 = excl;
    uint32_t* wp = wprefix + (size_t)b * WPB;
#pragma unroll
    for (int i = 0; i < 16; ++i) {
        wp[base + i] = off2;
        off2 += pc[i];
    }
}

// ---------------------------------------------------------------------------
// K3: stable stream compaction of {d3, dp} into per-batch float2 arrays
// (fixed stride HWSZ per batch). Ballot-rank from the bitmap word; writes of
// consecutive valid lanes land at consecutive destinations (coalesced).
// ---------------------------------------------------------------------------
__global__ __launch_bounds__(256) void k_compact(const float* __restrict__ d3,
                                                 const float* __restrict__ dp,
                                                 const uint64_t* __restrict__ words,
                                                 const uint32_t* __restrict__ wprefix,
                                                 float2* __restrict__ compact) {
    int gid = blockIdx.x * 256 + threadIdx.x;
    int w = gid >> 6;                  // wave-uniform word index
    int lane = threadIdx.x & 63;
    uint64_t word = words[w];
    bool valid = (word >> lane) & 1ull;
    if (valid) {
        uint32_t rank = (uint32_t)__popcll(word & ((1ull << lane) - 1ull));
        uint32_t dest = wprefix[w] + rank;       // within-batch position
        int b = blockIdx.x >> 10;                // 1024 blocks per batch
        compact[(size_t)b * HWSZ + dest] = make_float2(d3[gid], dp[gid]);
    }
}

// ---------------------------------------------------------------------------
// K4: sampling + loss. One 8B gather per endpoint from the compact array.
// Block-level reduction -> 4 atomics; last block finalizes the scalar output.
// ---------------------------------------------------------------------------
__global__ __launch_bounds__(256) void k_loss(const float2* __restrict__ compact,
                                              const int* __restrict__ s1raw,
                                              const int* __restrict__ s2raw,
                                              const uint32_t* __restrict__ valid_num,
                                              float* __restrict__ accf,
                                              uint32_t* __restrict__ accu,
                                              float* __restrict__ out) {
    __shared__ float sv1[4], sv2[4];
    __shared__ uint32_t sc1[4], sc2[4];

    int b = blockIdx.x >> 5;  // 32 blocks per batch
    int gid = blockIdx.x * 256 + threadIdx.x;

    uint32_t vn = valid_num[b];
    const float2* cb = compact + (size_t)b * HWSZ;

    uint32_t k1 = (uint32_t)s1raw[gid] % vn;
    uint32_t k2 = (uint32_t)s2raw[gid] % vn;

    float2 e1 = cb[k1];
    float2 e2 = cb[k2];

    float diff = e1.y - e2.y;
    bool gt = e1.x > e2.x + EPSV;
    bool lt = e1.x < e2.x - EPSV;
    float v1 = gt ? fmaxf(-diff, 0.0f) : 0.0f;
    float v2 = lt ? fmaxf(diff, 0.0f) : 0.0f;
    uint32_t c1 = gt ? 1u : 0u;
    uint32_t c2 = lt ? 1u : 0u;

    // wave (64-lane) reduction
#pragma unroll
    for (int off = 32; off > 0; off >>= 1) {
        v1 += __shfl_down(v1, off);
        v2 += __shfl_down(v2, off);
        c1 += __shfl_down(c1, off);
        c2 += __shfl_down(c2, off);
    }
    int wid = threadIdx.x >> 6;
    if ((threadIdx.x & 63) == 0) {
        sv1[wid] = v1; sv2[wid] = v2; sc1[wid] = c1; sc2[wid] = c2;
    }
    __syncthreads();
    if (threadIdx.x == 0) {
        float t1 = 0.f, t2 = 0.f;
        uint32_t u1 = 0, u2 = 0;
        for (int i = 0; i < 4; ++i) { t1 += sv1[i]; t2 += sv2[i]; u1 += sc1[i]; u2 += sc2[i]; }
        atomicAdd(&accf[0], t1);
        atomicAdd(&accf[1], t2);
        atomicAdd(&accu[0], u1);
        atomicAdd(&accu[1], u2);
        __threadfence();
        uint32_t ticket = atomicAdd(&accu[2], 1u);
        if (ticket == (uint32_t)(gridDim.x - 1)) {
            // all blocks' accumulator atomics happened-before their ticket
            // atomics (threadfence) -> atomic read-back sees the full sums.
            float sum1 = atomicAdd(&accf[0], 0.0f);
            float sum2 = atomicAdd(&accf[1], 0.0f);
            uint32_t n1 = atomicAdd(&accu[0], 0u);
            uint32_t n2 = atomicAdd(&accu[1], 0u);
            out[0] = 0.5f * (sum1 / (float)n1 + sum2 / (float)n2);
        }
    }
}

// ---------------------------------------------------------------------------
// Fallback path (no 64 MB compact buffer): round-1 rank/select k_loss.
// ---------------------------------------------------------------------------
__global__ __launch_bounds__(256) void k_loss_search(const float* __restrict__ d3,
                                                     const float* __restrict__ dp,
                                                     const int* __restrict__ s1raw,
                                                     const int* __restrict__ s2raw,
                                                     const uint64_t* __restrict__ words,
                                                     const uint32_t* __restrict__ wprefix,
                                                     const uint32_t* __restrict__ valid_num,
                                                     float* __restrict__ accf,
                                                     uint32_t* __restrict__ accu,
                                                     float* __restrict__ out) {
    __shared__ uint32_t wp[WPB];
    __shared__ float sv1[4], sv2[4];
    __shared__ uint32_t sc1[4], sc2[4];

    int b = blockIdx.x >> 5;
    int gid = blockIdx.x * 256 + threadIdx.x;

    const uint32_t* wpg = wprefix + (size_t)b * WPB;
    for (int i = threadIdx.x; i < WPB; i += 256) wp[i] = wpg[i];
    __syncthreads();

    uint32_t vn = valid_num[b];
    const uint64_t* wb = words + (size_t)b * WPB;
    const float* d3b = d3 + (size_t)b * HWSZ;
    const float* dpb = dp + (size_t)b * HWSZ;

    uint32_t k1 = (uint32_t)s1raw[gid] % vn;
    uint32_t k2 = (uint32_t)s2raw[gid] % vn;

    auto sel = [&](uint32_t k) -> int {
        int lo = 0, hi = WPB;
        while (hi - lo > 1) {
            int mid = (lo + hi) >> 1;
            if (wp[mid] <= k) lo = mid; else hi = mid;
        }
        uint32_t r = k - wp[lo];
        uint64_t x = wb[lo];
        int pos = lo << 6;
        uint32_t c = (uint32_t)__popcll(x & 0xFFFFFFFFull);
        if (r >= c) { r -= c; pos += 32; x >>= 32; }
        uint32_t y = (uint32_t)x;
        c = (uint32_t)__popc(y & 0xFFFFu); if (r >= c) { r -= c; pos += 16; y >>= 16; }
        c = (uint32_t)__popc(y & 0xFFu);   if (r >= c) { r -= c; pos += 8;  y >>= 8; }
        c = (uint32_t)__popc(y & 0xFu);    if (r >= c) { r -= c; pos += 4;  y >>= 4; }
        c = (uint32_t)__popc(y & 0x3u);    if (r >= c) { r -= c; pos += 2;  y >>= 2; }
        c = y & 1u;                        if (r >= c) { pos += 1; }
        return pos;
    };

    int i1 = sel(k1);
    int i2 = sel(k2);

    float a  = d3b[i1];
    float bv = d3b[i2];
    float diff = dpb[i1] - dpb[i2];

    bool gt = a > bv + EPSV;
    bool lt = a < bv - EPSV;
    float v1 = gt ? fmaxf(-diff, 0.0f) : 0.0f;
    float v2 = lt ? fmaxf(diff, 0.0f) : 0.0f;
    uint32_t c1 = gt ? 1u : 0u;
    uint32_t c2 = lt ? 1u : 0u;

#pragma unroll
    for (int off = 32; off > 0; off >>= 1) {
        v1 += __shfl_down(v1, off);
        v2 += __shfl_down(v2, off);
        c1 += __shfl_down(c1, off);
        c2 += __shfl_down(c2, off);
    }
    int wid = threadIdx.x >> 6;
    if ((threadIdx.x & 63) == 0) {
        sv1[wid] = v1; sv2[wid] = v2; sc1[wid] = c1; sc2[wid] = c2;
    }
    __syncthreads();
    if (threadIdx.x == 0) {
        float t1 = 0.f, t2 = 0.f;
        uint32_t u1 = 0, u2 = 0;
        for (int i = 0; i < 4; ++i) { t1 += sv1[i]; t2 += sv2[i]; u1 += sc1[i]; u2 += sc2[i]; }
        atomicAdd(&accf[0], t1);
        atomicAdd(&accf[1], t2);
        atomicAdd(&accu[0], u1);
        atomicAdd(&accu[1], u2);
        __threadfence();
        uint32_t ticket = atomicAdd(&accu[2], 1u);
        if (ticket == (uint32_t)(gridDim.x - 1)) {
            float sum1 = atomicAdd(&accf[0], 0.0f);
            float sum2 = atomicAdd(&accf[1], 0.0f);
            uint32_t n1 = atomicAdd(&accu[0], 0u);
            uint32_t n2 = atomicAdd(&accu[1], 0u);
            out[0] = 0.5f * (sum1 / (float)n1 + sum2 / (float)n2);
        }
    }
}

extern "C" void kernel_launch(void* const* d_in, const int* in_sizes, int n_in,
                              void* d_out, int out_size, void* d_ws, size_t ws_size,
                              hipStream_t stream) {
    const float* d3  = (const float*)d_in[0];  // depth_3dmm [B,1,H,W]
    const float* dp  = (const float*)d_in[1];  // depth_pigan [B,1,H,W]
    const int*  mask = (const int*)d_in[2];    // mask [B,1,H,W]
    const int*  s1   = (const int*)d_in[3];    // sample1_raw [B,P]
    const int*  s2   = (const int*)d_in[4];    // sample2_raw [B,P]
    float* out = (float*)d_out;

    char* ws = (char*)d_ws;
    uint64_t* words     = (uint64_t*)(ws);                 // 1,048,576 B
    uint32_t* wprefix   = (uint32_t*)(ws + 1048576);       //   524,288 B
    uint32_t* valid_num = (uint32_t*)(ws + 1572864);       //       128 B
    float*    accf      = (float*)(ws + 1573120);          // 2 floats
    uint32_t* accu      = (uint32_t*)(ws + 1573184);       // 3 uints (sums + done)
    float2*   compact   = (float2*)(ws + 2097152);         // 64 MiB worst-case

    const size_t need = 2097152 + (size_t)BB * HWSZ * sizeof(float2);

    k_bitmap<<<(BB * HWSZ) / 256, 256, 0, stream>>>(mask, words, accf, accu);
    k_scan<<<BB, 256, 0, stream>>>(words, wprefix, valid_num);

    if (ws_size >= need) {
        k_compact<<<(BB * HWSZ) / 256, 256, 0, stream>>>(d3, dp, words, wprefix, compact);
        k_loss<<<(BB * PP) / 256, 256, 0, stream>>>(compact, s1, s2, valid_num,
                                                    accf, accu, out);
    } else {
        k_loss_search<<<(BB * PP) / 256, 256, 0, stream>>>(d3, dp, s1, s2, words,
                                                           wprefix, valid_num,
                                                           accf, accu, out);
    }
}